// Round 5
// baseline (167.802 us; speedup 1.0000x reference)
//
#include <hip/hip_runtime.h>
#include <hip/hip_bf16.h>

// B=4,H=8,N=128,L=128,D=64.  out = softmax(mask? QK^T/8 : -2^15) @ V per head.
// One block per head (4096), 256 threads = 4 waves, wave owns 32 q-rows.
// S^T = mfma(K, Q^T) -> lane owns one q-row (q = lane&15): int4 mask loads,
// 2-shfl softmax, in-lane normalize. P relayout via per-wave swizzled LDS
// buffer overlaying the dead K region. O = mfma(P, V^T) -> coalesced scalar
// epilogue stores (proven zero write-amplification in round 2; the float4
// strided variant cost +98MB HBM traffic).
// LDS 32 KiB XOR-swizzled -> conflict-free b128 reads, 5 blocks/CU by LDS.

typedef __bf16 bf16;
typedef bf16 bf16x2 __attribute__((ext_vector_type(2)));
typedef bf16 bf16x4 __attribute__((ext_vector_type(4)));
typedef bf16 bf16x8 __attribute__((ext_vector_type(8)));
typedef float f32x4 __attribute__((ext_vector_type(4)));
typedef unsigned u32;

#define MFMA16(a, b, c) __builtin_amdgcn_mfma_f32_16x16x32_bf16((a), (b), (c), 0, 0, 0)

__global__ __launch_bounds__(256, 5) void attn_head_kernel(
    const float* __restrict__ q, const float* __restrict__ k,
    const float* __restrict__ v, const int* __restrict__ mask,
    float* __restrict__ out)
{
    constexpr int H = 8, N = 128, L = 128, D = 64;
    constexpr float QSCALE = 0.125f * 1.4426950408889634f;  // 1/8 * log2(e)

    __shared__ __align__(16) char SMEM[32768];
    char* KB = SMEM;           // K   [128 rows][128 B], granule16 ^ (row&7); dead after QK^T
    char* VB = SMEM + 16384;   // V^T [64 rows][256 B], granule16 ^ (row&15) ^ (row>>2)

    // XCD-aware swizzle (4096%8==0): 8 heads of one (b,n) share an XCD's L2.
    int bid  = blockIdx.x;
    int lidx = (bid & 7) * 512 + (bid >> 3);
    int h = lidx & 7, n = (lidx >> 3) & 127, b = lidx >> 10;

    const size_t base = (((size_t)(b * H + h)) * N + n) * (size_t)(L * D);
    const float* Qp = q + base;
    const float* Kp = k + base;
    const float* Vp = v + base;
    float*       Op = out + base;
    const int*   Mp = mask + ((size_t)(b * N + n)) * (size_t)(L * L);

    const int tid  = threadIdx.x;
    const int wave = tid >> 6;
    const int lane = tid & 63;
    const int g    = lane >> 4;
    const int c    = lane & 15;

    // ---- stage K -> KB (bf16, swizzled) ----
    #pragma unroll
    for (int i = 0; i < 8; ++i) {
        int e   = i * 256 + tid;
        int row = e >> 4;
        int d0  = (e & 15) * 4;
        float4 kv = ((const float4*)Kp)[e];
        bf16x4 pk4 = { (bf16)kv.x, (bf16)kv.y, (bf16)kv.z, (bf16)kv.w };
        int off = row * 128 + ((((d0 >> 3) ^ (row & 7)) << 4) | ((d0 & 4) << 1));
        *(bf16x4*)(KB + off) = pk4;
    }
    // ---- stage V -> VB (V^T, bf16, swizzled) via register 4x4 transpose ----
    #pragma unroll
    for (int i = 0; i < 2; ++i) {
        int id = i * 256 + tid;
        int db = id & 15;          // d-block (0..15)
        int kb = id >> 4;          // k-block (0..31)
        const float4* vp = (const float4*)(Vp + kb * 4 * 64 + db * 4);
        float4 r0 = vp[0], r1 = vp[16], r2 = vp[32], r3 = vp[48];
        bf16x4 w[4] = {
            { (bf16)r0.x, (bf16)r1.x, (bf16)r2.x, (bf16)r3.x },
            { (bf16)r0.y, (bf16)r1.y, (bf16)r2.y, (bf16)r3.y },
            { (bf16)r0.z, (bf16)r1.z, (bf16)r2.z, (bf16)r3.z },
            { (bf16)r0.w, (bf16)r1.w, (bf16)r2.w, (bf16)r3.w } };
        #pragma unroll
        for (int j = 0; j < 4; ++j) {
            int row = db * 4 + j;
            int gr  = (kb >> 1) ^ (row & 15) ^ (row >> 2);
            int off = row * 256 + (gr << 4) + ((kb & 1) * 8);
            *(bf16x4*)(VB + off) = w[j];
        }
    }

    // ---- Q B-fragments from global, pre-scaled (one bf16 rounding total) ----
    bf16x8 qb[2][2];
    #pragma unroll
    for (int rt = 0; rt < 2; ++rt)
        #pragma unroll
        for (int ds = 0; ds < 2; ++ds) {
            int row = wave * 32 + rt * 16 + c;
            const float4* qp = (const float4*)(Qp + row * D + ds * 32 + g * 8);
            float4 x0 = qp[0], x1 = qp[1];
            qb[rt][ds] = (bf16x8){
                (bf16)(x0.x * QSCALE), (bf16)(x0.y * QSCALE),
                (bf16)(x0.z * QSCALE), (bf16)(x0.w * QSCALE),
                (bf16)(x1.x * QSCALE), (bf16)(x1.y * QSCALE),
                (bf16)(x1.z * QSCALE), (bf16)(x1.w * QSCALE) };
        }

    __syncthreads();

    // ---- S^T = K Q^T : acc[kt][rt]; row(g*4+j)=k_local, col(c)=q_local ----
    f32x4 acc[8][2];
    #pragma unroll
    for (int kt = 0; kt < 8; ++kt)
        #pragma unroll
        for (int rt = 0; rt < 2; ++rt)
            acc[kt][rt] = (f32x4){0.f, 0.f, 0.f, 0.f};

    #pragma unroll
    for (int kt = 0; kt < 8; ++kt) {
        int row = kt * 16 + c;
        bf16x8 ka0 = *(const bf16x8*)(KB + row * 128 + (((g    ) ^ (row & 7)) << 4));
        bf16x8 ka1 = *(const bf16x8*)(KB + row * 128 + (((4 + g) ^ (row & 7)) << 4));
        #pragma unroll
        for (int rt = 0; rt < 2; ++rt) {
            acc[kt][rt] = MFMA16(ka0, qb[rt][0], acc[kt][rt]);
            acc[kt][rt] = MFMA16(ka1, qb[rt][1], acc[kt][rt]);
        }
    }

    __syncthreads();  // all waves done reading KB before P overlays it

    // ---- softmax in exp2-domain; lane owns q-row = wave*32 + rt*16 + c ----
    float rinv[2];
    #pragma unroll
    for (int rt = 0; rt < 2; ++rt) {
        int qrow = wave * 32 + rt * 16 + c;
        const int* mrow = Mp + (size_t)qrow * L;
        int4 mm[8];
        #pragma unroll
        for (int kt = 0; kt < 8; ++kt)
            mm[kt] = *(const int4*)(mrow + kt * 16 + g * 4);
        float mx = -3.0e38f;
        #pragma unroll
        for (int kt = 0; kt < 8; ++kt) {
            f32x4 a = acc[kt][rt];
            mx = fmaxf(mx, fmaxf(fmaxf(a[0], a[1]), fmaxf(a[2], a[3])));
        }
        mx = fmaxf(mx, __shfl_xor(mx, 16));
        mx = fmaxf(mx, __shfl_xor(mx, 32));
        float sum = 0.f;
        #pragma unroll
        for (int kt = 0; kt < 8; ++kt) {
            float e0 = __builtin_amdgcn_exp2f(acc[kt][rt][0] - mx);
            float e1 = __builtin_amdgcn_exp2f(acc[kt][rt][1] - mx);
            float e2 = __builtin_amdgcn_exp2f(acc[kt][rt][2] - mx);
            float e3 = __builtin_amdgcn_exp2f(acc[kt][rt][3] - mx);
            e0 = mm[kt].x ? e0 : 0.f;
            e1 = mm[kt].y ? e1 : 0.f;
            e2 = mm[kt].z ? e2 : 0.f;
            e3 = mm[kt].w ? e3 : 0.f;
            acc[kt][rt][0] = e0; acc[kt][rt][1] = e1;
            acc[kt][rt][2] = e2; acc[kt][rt][3] = e3;
            sum += (e0 + e1) + (e2 + e3);
        }
        sum += __shfl_xor(sum, 16);
        sum += __shfl_xor(sum, 32);
        rinv[rt] = __builtin_amdgcn_rcpf(sum);
    }

    // ---- O = P V : P (normalized bf16) via per-wave swizzled LDS overlay ----
    // PW: [32 q-rows][128 B] per wave, granule16 ^ (row&7). Two k-half passes.
    char* PW = SMEM + wave * 4096;
    f32x4 oacc[2][4];
    #pragma unroll
    for (int rt = 0; rt < 2; ++rt)
        #pragma unroll
        for (int dt = 0; dt < 4; ++dt)
            oacc[rt][dt] = (f32x4){0.f, 0.f, 0.f, 0.f};

    #pragma unroll
    for (int pp = 0; pp < 2; ++pp) {
        // write normalized P (bf16) for k_local in [0,64): packed 8B writes
        #pragma unroll
        for (int rt = 0; rt < 2; ++rt) {
            float r = rinv[rt];
            int row = rt * 16 + c;
            #pragma unroll
            for (int t = 0; t < 4; ++t) {
                f32x4 a = acc[pp * 4 + t][rt];
                bf16x4 w = { (bf16)(a[0] * r), (bf16)(a[1] * r),
                             (bf16)(a[2] * r), (bf16)(a[3] * r) };
                int kl  = t * 16 + g * 4;
                int off = row * 128 + ((((kl >> 3) ^ (row & 7)) << 4) | ((kl & 4) << 1));
                *(bf16x4*)(PW + off) = w;
            }
        }
        // wave-local ordering: LDS is in-order per wave; drain then fence sched
        asm volatile("s_waitcnt lgkmcnt(0)" ::: "memory");
        __builtin_amdgcn_sched_barrier(0);

        #pragma unroll
        for (int kc2 = 0; kc2 < 2; ++kc2) {
            int kc = pp * 2 + kc2;
            bf16x8 va[4];
            #pragma unroll
            for (int dt = 0; dt < 4; ++dt) {
                int row = dt * 16 + c;
                int gr  = (kc * 4 + g) ^ (row & 15) ^ (row >> 2);
                va[dt] = *(const bf16x8*)(VB + row * 256 + (gr << 4));
            }
            #pragma unroll
            for (int rt = 0; rt < 2; ++rt) {
                int row = rt * 16 + c;
                int gr  = (kc2 * 4 + g) ^ (row & 7);
                bf16x8 pa = *(const bf16x8*)(PW + row * 128 + (gr << 4));
                #pragma unroll
                for (int dt = 0; dt < 4; ++dt)
                    oacc[rt][dt] = MFMA16(pa, va[dt], oacc[rt][dt]);  // O = P V
            }
        }
        asm volatile("" ::: "memory");  // keep pass-1 writes after pass-0 reads
    }

    // ---- store: O[q][d], q-row = wave*32+rt*16+g*4+j, col d = dt*16+c.
    // Scalar dword stores, consecutive lanes -> consecutive addresses
    // (round-2-proven: WRITE_SIZE == output size exactly, no amplification).
    #pragma unroll
    for (int rt = 0; rt < 2; ++rt)
        #pragma unroll
        for (int j = 0; j < 4; ++j) {
            int row = wave * 32 + rt * 16 + g * 4 + j;
            float* orow = Op + (size_t)row * D;
            #pragma unroll
            for (int dt = 0; dt < 4; ++dt)
                orow[dt * 16 + c] = oacc[rt][dt][j];
        }
}

extern "C" void kernel_launch(void* const* d_in, const int* in_sizes, int n_in,
                              void* d_out, int out_size, void* d_ws, size_t ws_size,
                              hipStream_t stream) {
    const float* q    = (const float*)d_in[0];
    const float* k    = (const float*)d_in[1];
    const float* v    = (const float*)d_in[2];
    const int*   mask = (const int*)d_in[3];
    float*       out  = (float*)d_out;
    attn_head_kernel<<<4096, 256, 0, stream>>>(q, k, v, mask, out);
}

// Round 6
// 123.202 us; speedup vs baseline: 1.3620x; 1.3620x over previous
//
#include <hip/hip_runtime.h>
#include <hip/hip_bf16.h>

// B=4,H=8,N=128,L=128,D=64.  out = softmax(mask? QK^T/8 : -2^15) @ V per head.
// One block per head (4096), 512 threads = 8 waves, wave owns 16 q-rows.
// Rationale: occupancy is REGISTER-capped (acc lives in unified VGPR/AGPR
// file; 256-thread version ~160 regs/lane -> 12.8 waves/CU = the measured
// 40%). Halving per-thread accumulator state (acc[8]+oacc[4] = 48 f32)
// roughly doubles resident waves. Layouts are the round-2-proven ones
// (padded KL/VT, P overlay on dead K region, scalar coalesced stores).
// S^T = mfma(K, Q^T) -> lane owns one q-row; int4 mask loads, 2-shfl softmax,
// exp2-domain with log2e folded into the Q prescale (round-4/5-proven).

typedef __bf16 bf16;
typedef bf16 bf16x4 __attribute__((ext_vector_type(4)));
typedef bf16 bf16x8 __attribute__((ext_vector_type(8)));
typedef float f32x4 __attribute__((ext_vector_type(4)));

#define MFMA16(a, b, c) __builtin_amdgcn_mfma_f32_16x16x32_bf16((a), (b), (c), 0, 0, 0)

__global__ __launch_bounds__(512, 4) void attn_head_kernel(
    const float* __restrict__ q, const float* __restrict__ k,
    const float* __restrict__ v, const int* __restrict__ mask,
    float* __restrict__ out)
{
    constexpr int H = 8, N = 128, L = 128, D = 64;
    constexpr float QSCALE = 0.125f * 1.4426950408889634f;  // 1/8 * log2(e)

    __shared__ bf16 KL[128][72];    // 18432 B; dead after QK^T, P overlays it
    __shared__ bf16 VT[64][136];    // 17408 B

    // XCD-aware swizzle (4096%8==0): 8 heads of one (b,n) share an XCD's L2.
    int bid  = blockIdx.x;
    int lidx = (bid & 7) * 512 + (bid >> 3);
    int h = lidx & 7, n = (lidx >> 3) & 127, b = lidx >> 10;

    const size_t base = (((size_t)(b * H + h)) * N + n) * (size_t)(L * D);
    const float* Qp = q + base;
    const float* Kp = k + base;
    const float* Vp = v + base;
    float*       Op = out + base;
    const int*   Mp = mask + ((size_t)(b * N + n)) * (size_t)(L * L);

    const int tid  = threadIdx.x;
    const int wave = tid >> 6;    // 0..7, owns q-rows [wave*16, wave*16+16)
    const int lane = tid & 63;
    const int g    = lane >> 4;
    const int c    = lane & 15;

    // ---- stage K -> KL (bf16, packed b64 writes), 4 float4 per thread ----
    #pragma unroll
    for (int i = 0; i < 4; ++i) {
        int e   = i * 512 + tid;
        int row = e >> 4;
        int d0  = (e & 15) * 4;
        float4 kv = ((const float4*)Kp)[e];
        bf16x4 pk4 = { (bf16)kv.x, (bf16)kv.y, (bf16)kv.z, (bf16)kv.w };
        *(bf16x4*)&KL[row][d0] = pk4;
    }
    // ---- stage V -> VT via register 4x4 transpose, 1 block per thread ----
    {
        int db = tid & 15;         // d-block (0..15)
        int kb = tid >> 4;         // k-block (0..31)
        const float4* vp = (const float4*)(Vp + kb * 4 * 64 + db * 4);
        float4 r0 = vp[0], r1 = vp[16], r2 = vp[32], r3 = vp[48];
        bf16x4 w0 = { (bf16)r0.x, (bf16)r1.x, (bf16)r2.x, (bf16)r3.x };
        bf16x4 w1 = { (bf16)r0.y, (bf16)r1.y, (bf16)r2.y, (bf16)r3.y };
        bf16x4 w2 = { (bf16)r0.z, (bf16)r1.z, (bf16)r2.z, (bf16)r3.z };
        bf16x4 w3 = { (bf16)r0.w, (bf16)r1.w, (bf16)r2.w, (bf16)r3.w };
        *(bf16x4*)&VT[db * 4 + 0][kb * 4] = w0;
        *(bf16x4*)&VT[db * 4 + 1][kb * 4] = w1;
        *(bf16x4*)&VT[db * 4 + 2][kb * 4] = w2;
        *(bf16x4*)&VT[db * 4 + 3][kb * 4] = w3;
    }

    // ---- Q B-fragment from global, pre-scaled (one bf16 rounding total) ----
    bf16x8 qb[2];
    #pragma unroll
    for (int ds = 0; ds < 2; ++ds) {
        int row = wave * 16 + c;
        const float4* qp = (const float4*)(Qp + row * D + ds * 32 + g * 8);
        float4 x0 = qp[0], x1 = qp[1];
        qb[ds] = (bf16x8){
            (bf16)(x0.x * QSCALE), (bf16)(x0.y * QSCALE),
            (bf16)(x0.z * QSCALE), (bf16)(x0.w * QSCALE),
            (bf16)(x1.x * QSCALE), (bf16)(x1.y * QSCALE),
            (bf16)(x1.z * QSCALE), (bf16)(x1.w * QSCALE) };
    }

    __syncthreads();

    // ---- S^T = K Q^T : acc[kt]; row(g*4+j)=k_local, col(c)=q_local ----
    f32x4 acc[8];
    #pragma unroll
    for (int kt = 0; kt < 8; ++kt)
        acc[kt] = (f32x4){0.f, 0.f, 0.f, 0.f};

    #pragma unroll
    for (int kt = 0; kt < 8; ++kt) {
        int row = kt * 16 + c;
        bf16x8 ka0 = *(const bf16x8*)&KL[row][g * 8];
        bf16x8 ka1 = *(const bf16x8*)&KL[row][32 + g * 8];
        acc[kt] = MFMA16(ka0, qb[0], acc[kt]);
        acc[kt] = MFMA16(ka1, qb[1], acc[kt]);
    }

    __syncthreads();  // all waves done reading KL before P overlays it

    // ---- softmax in exp2-domain; lane owns q-row = wave*16 + c ----
    float rinv;
    {
        int qrow = wave * 16 + c;
        const int* mrow = Mp + (size_t)qrow * L;
        int4 mm[8];
        #pragma unroll
        for (int kt = 0; kt < 8; ++kt)
            mm[kt] = *(const int4*)(mrow + kt * 16 + g * 4);
        float mx = -3.0e38f;
        #pragma unroll
        for (int kt = 0; kt < 8; ++kt) {
            f32x4 a = acc[kt];
            mx = fmaxf(mx, fmaxf(fmaxf(a[0], a[1]), fmaxf(a[2], a[3])));
        }
        mx = fmaxf(mx, __shfl_xor(mx, 16));
        mx = fmaxf(mx, __shfl_xor(mx, 32));
        float sum = 0.f;
        #pragma unroll
        for (int kt = 0; kt < 8; ++kt) {
            float e0 = __builtin_amdgcn_exp2f(acc[kt][0] - mx);
            float e1 = __builtin_amdgcn_exp2f(acc[kt][1] - mx);
            float e2 = __builtin_amdgcn_exp2f(acc[kt][2] - mx);
            float e3 = __builtin_amdgcn_exp2f(acc[kt][3] - mx);
            e0 = mm[kt].x ? e0 : 0.f;
            e1 = mm[kt].y ? e1 : 0.f;
            e2 = mm[kt].z ? e2 : 0.f;
            e3 = mm[kt].w ? e3 : 0.f;
            acc[kt][0] = e0; acc[kt][1] = e1;
            acc[kt][2] = e2; acc[kt][3] = e3;
            sum += (e0 + e1) + (e2 + e3);
        }
        sum += __shfl_xor(sum, 16);
        sum += __shfl_xor(sum, 32);
        rinv = __builtin_amdgcn_rcpf(sum);
    }

    // ---- O = P V : P (normalized bf16) via per-wave LDS overlay on KL ----
    // PLw: [16 q-rows][72] bf16 per wave (2304 B; 8 waves fill KL exactly).
    bf16* PLw = &KL[0][0] + wave * (16 * 72);
    f32x4 oacc[4];
    #pragma unroll
    for (int dt = 0; dt < 4; ++dt)
        oacc[dt] = (f32x4){0.f, 0.f, 0.f, 0.f};

    #pragma unroll
    for (int pp = 0; pp < 2; ++pp) {
        // write normalized P (bf16) for k_local in [pp*64, pp*64+64)
        #pragma unroll
        for (int t = 0; t < 4; ++t) {
            f32x4 a = acc[pp * 4 + t];
            bf16x4 w = { (bf16)(a[0] * rinv), (bf16)(a[1] * rinv),
                         (bf16)(a[2] * rinv), (bf16)(a[3] * rinv) };
            *(bf16x4*)&PLw[c * 72 + t * 16 + g * 4] = w;
        }
        // wave-local ordering: LDS in-order per wave; drain then fence sched
        asm volatile("s_waitcnt lgkmcnt(0)" ::: "memory");
        __builtin_amdgcn_sched_barrier(0);

        #pragma unroll
        for (int kc2 = 0; kc2 < 2; ++kc2) {
            int kc = pp * 2 + kc2;
            bf16x8 va[4];
            #pragma unroll
            for (int dt = 0; dt < 4; ++dt)
                va[dt] = *(const bf16x8*)&VT[dt * 16 + c][kc * 32 + g * 8];
            bf16x8 pa = *(const bf16x8*)&PLw[c * 72 + kc2 * 32 + g * 8];
            #pragma unroll
            for (int dt = 0; dt < 4; ++dt)
                oacc[dt] = MFMA16(pa, va[dt], oacc[dt]);  // O = P V
        }
        asm volatile("" ::: "memory");  // keep pass-1 writes after pass-0 reads
    }

    // ---- store: O[q][d], q-row = wave*16 + g*4 + j, col d = dt*16 + c ----
    // Scalar dword stores, consecutive lanes -> consecutive addresses.
    #pragma unroll
    for (int j = 0; j < 4; ++j) {
        int row = wave * 16 + g * 4 + j;
        float* orow = Op + (size_t)row * D;
        #pragma unroll
        for (int dt = 0; dt < 4; ++dt)
            orow[dt * 16 + c] = oacc[dt][j];
    }
}

extern "C" void kernel_launch(void* const* d_in, const int* in_sizes, int n_in,
                              void* d_out, int out_size, void* d_ws, size_t ws_size,
                              hipStream_t stream) {
    const float* q    = (const float*)d_in[0];
    const float* k    = (const float*)d_in[1];
    const float* v    = (const float*)d_in[2];
    const int*   mask = (const int*)d_in[3];
    float*       out  = (float*)d_out;
    attn_head_kernel<<<4096, 512, 0, stream>>>(q, k, v, mask, out);
}